// Round 15
// baseline (470.169 us; speedup 1.0000x reference)
//
#include <hip/hip_runtime.h>
#include <hip/hip_bf16.h>
#include <stdint.h>

#define TSTEPS 4

typedef __bf16 bf16_t;
typedef __attribute__((ext_vector_type(8))) __bf16 bf16x8;
typedef __attribute__((ext_vector_type(16))) float f32x16;
typedef __attribute__((ext_vector_type(4))) unsigned short ushort4v;

union frag_u { bf16x8 v; uint32_t d[4]; unsigned short u[8]; };

// gfx9 s_waitcnt immediates: vmcnt low4 [3:0] hi2 [15:14]; expcnt=7,lgkm=15 off
#define VMCNT6  0xF76
#define VMCNT0  0xF70

// ---------------------------------------------------------------------------
// Spike i8 layout: [m_blk32][kb16][t][row0..31][16 bytes] (byte j = spike at
// k-offset j in the 16-wide kb; value 0/1). 4 MB enc / 32 MB per hidden
// tensor. GEMM expands bytes -> exact 0/1 bf16 via v_perm + mul (2 ops/dword,
// vs R14's ~23 ops/dword cndmask chains): MFMA inputs bitwise-identical.
// ---------------------------------------------------------------------------

// ---------------------------------------------------------------------------
// Stage 1: input LIF encoder -> spike i8 bytes. C=128. XLA-exact LIF.
// One thread per (m_blk, kb, row): 16 k-floats -> 4 x uint4 stores (one per t).
// ---------------------------------------------------------------------------
__global__ void spike_encode_i8(const float* __restrict__ x,
                                uint4* __restrict__ s1)
{
    const int C = 128;
    int tid = blockIdx.x * blockDim.x + threadIdx.x;  // 65536 = 256*8*32
    int row = tid & 31;
    int kb  = (tid >> 5) & 7;
    int m_blk = tid >> 8;
    int m = m_blk * 32 + row;
    const float* px = x + (size_t)m * C + kb * 16;
    float xv[16];
#pragma unroll
    for (int j = 0; j < 16; j += 4) {
        float4 t4 = *(const float4*)(px + j);
        xv[j] = t4.x; xv[j+1] = t4.y; xv[j+2] = t4.z; xv[j+3] = t4.w;
    }
    float v[16];
#pragma unroll
    for (int j = 0; j < 16; ++j) v[j] = 0.0f;
#pragma unroll
    for (int t = 0; t < TSTEPS; ++t) {
        uint32_t dw[4] = {0u, 0u, 0u, 0u};
#pragma unroll
        for (int j = 0; j < 16; ++j) {
            float vv = __fadd_rn(v[j], __fmul_rn(__fsub_rn(xv[j], v[j]), 0.5f));
            bool sp = (vv >= 1.0f);
            dw[j >> 2] |= sp ? (1u << ((j & 3) * 8)) : 0u;
            v[j] = sp ? 0.0f : vv;
        }
        uint4 o; o.x = dw[0]; o.y = dw[1]; o.z = dw[2]; o.w = dw[3];
        s1[((size_t)(m_blk * 8 + kb) * 4 + t) * 32 + row] = o;
    }
}

// ---------------------------------------------------------------------------
// Weight prep: W [K][N] fp32 -> hi/lo bf16 split in B-frag layout.
// ---------------------------------------------------------------------------
__global__ void split_transpose_all(const float* __restrict__ enc_W,
                                    const float* __restrict__ W_cells,
                                    bf16_t* __restrict__ W1h, bf16_t* __restrict__ W1l,
                                    bf16_t* __restrict__ W2h, bf16_t* __restrict__ W2l,
                                    bf16_t* __restrict__ W3h, bf16_t* __restrict__ W3l)
{
    const int N = 1024;
    const float* W;
    bf16_t *hi, *lo;
    int K;
    if (blockIdx.z == 0) {
        if (blockIdx.x >= 4) return;
        W = enc_W; hi = W1h; lo = W1l; K = 128;
    } else if (blockIdx.z == 1) {
        W = W_cells; hi = W2h; lo = W2l; K = 1024;
    } else {
        W = W_cells + (size_t)1024 * 1024; hi = W3h; lo = W3l; K = 1024;
    }
    const int NKB = K >> 4;
    __shared__ float tile[32][33];
    int k0 = blockIdx.x * 32, n0 = blockIdx.y * 32;
    int tx = threadIdx.x & 31, ty = threadIdx.x >> 5;
    for (int kk = ty; kk < 32; kk += 8)
        tile[kk][tx] = W[(size_t)(k0 + kk) * N + n0 + tx];
    __syncthreads();
    for (int nn = ty; nn < 32; nn += 8) {
        float wv = tile[tx][nn];
        bf16_t h = (bf16_t)wv;
        bf16_t l = (bf16_t)(wv - (float)h);
        int n = n0 + nn, k = k0 + tx;
        size_t o = ((size_t)(n >> 5) * NKB + (k >> 4)) * 512
                 + (size_t)((n & 31) + ((k >> 3) & 1) * 32) * 8 + (k & 7);
        hi[o] = h;
        lo[o] = l;
    }
}

// ---------------------------------------------------------------------------
// Fused MFMA GEMM + multistep LIF.  R15 = R14 with i8 spikes + perm/mul expand.
// A = spike i8 bytes; B = hi/lo bf16 frag-order. Block: 256 thr, 4 waves of
// 32m x 32n (2x2) -> 64x64 tile; tau=4; acc[4t] f32x16 = 64 AGPR.
// K-loop per kb16: 6 loads (4 A dwordx2 + 2 B dwordx4), ring-2, vmcnt(6);
// expand: per dword v_perm_b32 ([b0,0,b1,0]) then * 0x3F80 -> exact 0/1 bf16
// (2 ops/dword = 64 VALU cyc/kb vs R14's ~368 cndmask chains).
// Per-acc MFMA order unchanged (hi t0..t3, lo t0..t3, kb ascending) ->
// bitwise-identical accumulators -> absmax 0.0 preserved.
// Epilogue: ballot -> wave-private LDS masks -> nibble-spread expand ->
// coalesced uint4 (16B) i8 stores for the next layer.
// ---------------------------------------------------------------------------
template <int K, bool LAST>
__global__ __launch_bounds__(256, 3)
void gemm_lif_mfma(const uint8_t* __restrict__ Abytes,
                   const bf16_t* __restrict__ Bh,
                   const bf16_t* __restrict__ Bl,
                   const float* __restrict__ bias,
                   uint8_t* __restrict__ Sbytes,
                   float* __restrict__ Out,
                   int M, int N)
{
    constexpr int NKB = K >> 4;                 // 8 or 64 (even)
    __shared__ __align__(8) unsigned short sh[4][256];   // [wave][row][kb][t]

    const int tid = threadIdx.x;
    const int lane = tid & 63;
    const int wid = tid >> 6;
    const int l31 = lane & 31;
    const int half = lane >> 5;

    int bid = blockIdx.x;
    const int n_t = bid & 15;                   // 16 n-tiles of 64 (2 per XCD)
    const int m_t = bid >> 4;                   // 128 m-tiles of 64
    const int m0 = m_t * 64, n0 = n_t * 64;
    const int wave_m = (wid & 1) * 32;
    const int wave_n = (wid >> 1) * 32;
    const int m_blk = (m0 + wave_m) >> 5;
    const int n_blk = (n0 + wave_n) >> 5;

    const uint8_t* pA = Abytes + (size_t)m_blk * NKB * 4 * 512 + l31 * 16 + half * 8;
    const bf16_t* pH = Bh + (size_t)n_blk * NKB * 512 + lane * 8;
    const bf16_t* pL = Bl + (size_t)n_blk * NKB * 512 + lane * 8;

    f32x16 acc[TSTEPS];
#pragma unroll
    for (int t = 0; t < TSTEPS; ++t)
        for (int rr = 0; rr < 16; ++rr) acc[t][rr] = 0.0f;

    uint2 fm[2][4];
    bf16x8 fh[2], fl[2];

#define LOADB(kb_, s_) {                                                     \
        fm[s_][0] = *(const uint2*)(pA + ((size_t)(kb_) * 4 + 0) * 512);     \
        fm[s_][1] = *(const uint2*)(pA + ((size_t)(kb_) * 4 + 1) * 512);     \
        fm[s_][2] = *(const uint2*)(pA + ((size_t)(kb_) * 4 + 2) * 512);     \
        fm[s_][3] = *(const uint2*)(pA + ((size_t)(kb_) * 4 + 3) * 512);     \
        fh[s_] = *(const bf16x8*)(pH + (kb_) * 512);                         \
        fl[s_] = *(const bf16x8*)(pL + (kb_) * 512);                         \
    }

// bytes (0/1) -> bf16 frag: perm spreads [b0,0,b1,0]; dword = b0 + b1<<16;
// * 0x3F80 -> (b0?0x3F80:0)|(b1?0x3F800000:0). Exact.
#define EXPANDF(a_, f_) {                                                    \
        (f_).d[0] = __builtin_amdgcn_perm((a_).x, 0u, 0x00050004u) * 0x3F80u; \
        (f_).d[1] = __builtin_amdgcn_perm((a_).x, 0u, 0x00070006u) * 0x3F80u; \
        (f_).d[2] = __builtin_amdgcn_perm((a_).y, 0u, 0x00050004u) * 0x3F80u; \
        (f_).d[3] = __builtin_amdgcn_perm((a_).y, 0u, 0x00070006u) * 0x3F80u; \
    }

#define MFMASTEP(s_) {                                                       \
        frag_u af0, af1, af2, af3;                                           \
        EXPANDF(fm[s_][0], af0);                                             \
        EXPANDF(fm[s_][1], af1);                                             \
        EXPANDF(fm[s_][2], af2);                                             \
        EXPANDF(fm[s_][3], af3);                                             \
        acc[0] = __builtin_amdgcn_mfma_f32_32x32x16_bf16(af0.v, fh[s_], acc[0], 0, 0, 0); \
        acc[1] = __builtin_amdgcn_mfma_f32_32x32x16_bf16(af1.v, fh[s_], acc[1], 0, 0, 0); \
        acc[2] = __builtin_amdgcn_mfma_f32_32x32x16_bf16(af2.v, fh[s_], acc[2], 0, 0, 0); \
        acc[3] = __builtin_amdgcn_mfma_f32_32x32x16_bf16(af3.v, fh[s_], acc[3], 0, 0, 0); \
        acc[0] = __builtin_amdgcn_mfma_f32_32x32x16_bf16(af0.v, fl[s_], acc[0], 0, 0, 0); \
        acc[1] = __builtin_amdgcn_mfma_f32_32x32x16_bf16(af1.v, fl[s_], acc[1], 0, 0, 0); \
        acc[2] = __builtin_amdgcn_mfma_f32_32x32x16_bf16(af2.v, fl[s_], acc[2], 0, 0, 0); \
        acc[3] = __builtin_amdgcn_mfma_f32_32x32x16_bf16(af3.v, fl[s_], acc[3], 0, 0, 0); \
    }

#define STEP(kb_, s_) {                                                      \
        if ((kb_) + 1 < NKB) {                                               \
            LOADB((kb_) + 1, (s_) ^ 1);                                      \
            __builtin_amdgcn_s_waitcnt(VMCNT6);                              \
        } else {                                                             \
            __builtin_amdgcn_s_waitcnt(VMCNT0);                              \
        }                                                                    \
        asm volatile("" ::: "memory");                                       \
        MFMASTEP(s_);                                                        \
    }

    LOADB(0, 0);
#pragma unroll 2
    for (int kb = 0; kb < NKB; kb += 2) {
        STEP(kb + 0, 0);
        STEP(kb + 1, 1);
    }

#undef STEP
#undef MFMASTEP
#undef EXPANDF
#undef LOADB

    // --- LIF epilogue: t-scan in registers (XLA-exact arithmetic) ---
    const float bv = bias[n0 + wave_n + l31];
    f32x16 vmem;
#pragma unroll
    for (int rr = 0; rr < 16; ++rr) vmem[rr] = 0.0f;
    uint64_t bits = 0ull;
    unsigned short* myt = &sh[wid][0];          // [row][kb][t] = [32][2][4]

    const int NKBo = N >> 4;
    const int kbase = (n0 + wave_n) >> 4;

    for (int t = 0; t < TSTEPS; ++t) {
#pragma unroll
        for (int rr = 0; rr < 16; ++rr) {
            float y = __fadd_rn(acc[t][rr], bv);
            float vv = vmem[rr];
            vv = __fadd_rn(vv, __fmul_rn(__fsub_rn(y, vv), 0.5f));
            bool sp = (vv >= 1.0f);
            vmem[rr] = sp ? 0.0f : vv;
            if (LAST) {
                bits |= sp ? (1ull << (rr * 4 + t)) : 0ull;
            } else {
                // ballot: low32 = row r0 (lanes = cols), high32 = row r0+4
                unsigned long long b = __ballot(sp);
                if (l31 == 0) {
                    uint32_t hb = (uint32_t)(b >> (half * 32));
                    int rowi = (rr & 3) + 8 * (rr >> 2) + 4 * half;
                    myt[(rowi * 2 + 0) * 4 + t] = (unsigned short)hb;
                    myt[(rowi * 2 + 1) * 4 + t] = (unsigned short)(hb >> 16);
                }
            }
        }
    }

    if (LAST) {
#pragma unroll
        for (int rr = 0; rr < 16; ++rr) {
            int m_r = (rr & 3) + 8 * (rr >> 2) + 4 * half;
            int m = m0 + wave_m + m_r;
            int n = n0 + wave_n + l31;
            int cnt = __popc((unsigned)((bits >> (rr * 4)) & 0xFull));
            Out[(size_t)m * N + n] = 0.25f * (float)cnt;
        }
    } else {
        // lane (row=l31, kb=kbase+half): expand 16-bit mask -> 16 i8 bytes
        // per t (nibble-spread: *0x00204081 & 0x01010101), coalesced 16B store
        const ushort4v pk = *(const ushort4v*)&myt[(l31 * 2 + half) * 4];
#pragma unroll
        for (int t = 0; t < TSTEPS; ++t) {
            uint32_t m16 = pk[t];
            uint4 o;
            o.x = ((m16      ) & 0xFu) * 0x00204081u & 0x01010101u;
            o.y = ((m16 >>  4) & 0xFu) * 0x00204081u & 0x01010101u;
            o.z = ((m16 >>  8) & 0xFu) * 0x00204081u & 0x01010101u;
            o.w = ((m16 >> 12) & 0xFu) * 0x00204081u & 0x01010101u;
            *(uint4*)(Sbytes + ((((size_t)m_blk * NKBo + kbase + half) * 4 + t)
                                * 32 + l31) * 16) = o;
        }
    }
}

// ---------------------------------------------------------------------------
// out2[b][d] = mean over L of out[b][l][d]. Exact in fp32 (quarter-integers).
// ---------------------------------------------------------------------------
__global__ void mean_over_L_kernel(const float* __restrict__ out,
                                   float* __restrict__ out2,
                                   int B, int L, int D)
{
    int id = blockIdx.x * blockDim.x + threadIdx.x;
    if (id >= B * D) return;
    int b = id / D, d = id - b * D;
    const float* p = out + (size_t)b * L * D + d;
    float s = 0.0f;
    for (int l = 0; l < L; ++l) s += p[(size_t)l * D];
    out2[id] = s * (1.0f / (float)L);
}

// ---------------------------------------------------------------------------
extern "C" void kernel_launch(void* const* d_in, const int* in_sizes, int n_in,
                              void* d_out, int out_size, void* d_ws, size_t ws_size,
                              hipStream_t stream)
{
    const float* inputs  = (const float*)d_in[0];  // [16,512,128]
    const float* enc_W   = (const float*)d_in[1];  // [128,1024]
    const float* enc_b   = (const float*)d_in[2];  // [1024]
    const float* W_cells = (const float*)d_in[3];  // [2,1024,1024]
    const float* b_cells = (const float*)d_in[4];  // [2,1024]

    const int B = 16, L = 512, C = 128, D = 1024;
    const int M = B * L;  // 8192

    // ws: s1 i8 4MB | W1h/l 0.5MB | W2h/l 4MB | W3h/l 4MB | h0 32MB | h1 32MB
    char* ws = (char*)d_ws;
    size_t off = 0;
    uint8_t* s1 = (uint8_t*)(ws + off);
    off += (size_t)(M / 32) * (C / 16) * 4 * 32 * 16;
    bf16_t* W1h = (bf16_t*)(ws + off); off += (size_t)C * D * 2;
    bf16_t* W1l = (bf16_t*)(ws + off); off += (size_t)C * D * 2;
    bf16_t* W2h = (bf16_t*)(ws + off); off += (size_t)D * D * 2;
    bf16_t* W2l = (bf16_t*)(ws + off); off += (size_t)D * D * 2;
    bf16_t* W3h = (bf16_t*)(ws + off); off += (size_t)D * D * 2;
    bf16_t* W3l = (bf16_t*)(ws + off); off += (size_t)D * D * 2;
    uint8_t* h0 = (uint8_t*)(ws + off);
    off += (size_t)(M / 32) * (D / 16) * 4 * 32 * 16;
    uint8_t* h1 = (uint8_t*)(ws + off);

    float* out  = (float*)d_out;          // [M, D]
    float* out2 = out + (size_t)M * D;    // [B, D]

    split_transpose_all<<<dim3(32, 32, 3), 256, 0, stream>>>(
        enc_W, W_cells, W1h, W1l, W2h, W2l, W3h, W3l);

    spike_encode_i8<<<256, 256, 0, stream>>>(inputs, (uint4*)s1);

    const int nblocks = (M / 64) * (D / 64);   // 2048
    gemm_lif_mfma<128, false><<<nblocks, 256, 0, stream>>>(
        s1, W1h, W1l, enc_b, h0, nullptr, M, D);
    gemm_lif_mfma<1024, false><<<nblocks, 256, 0, stream>>>(
        h0, W2h, W2l, b_cells, h1, nullptr, M, D);
    gemm_lif_mfma<1024, true><<<nblocks, 256, 0, stream>>>(
        h1, W3h, W3l, b_cells + D, nullptr, out, M, D);

    mean_over_L_kernel<<<(B * D + 255) / 256, 256, 0, stream>>>(
        out, out2, B, L, D);
}

// Round 17
// 359.170 us; speedup vs baseline: 1.3090x; 1.3090x over previous
//
#include <hip/hip_runtime.h>
#include <hip/hip_bf16.h>
#include <stdint.h>

#define TSTEPS 4

typedef __bf16 bf16_t;
typedef __attribute__((ext_vector_type(8))) __bf16 bf16x8;
typedef __attribute__((ext_vector_type(16))) float f32x16;
typedef __attribute__((ext_vector_type(4))) unsigned short ushort4v;

union frag_u { bf16x8 v; uint32_t d[4]; unsigned short u[8]; };

// gfx9 s_waitcnt immediates: vmcnt low4 [3:0] hi2 [15:14]; expcnt=7,lgkm=15 off
#define VMCNT6  0xF76
#define VMCNT0  0xF70

// ---------------------------------------------------------------------------
// Spike i8 layout: [m_blk32][kb16][t][row0..31][16 bytes] (byte j = spike at
// k-offset j in the 16-wide kb; value 0/1). Expanded in-register to exact
// 0/1 bf16 via v_perm+mul -> MFMA inputs bitwise-identical to bf16 storage.
// B-frag layout: packet ((n>>5)*NKB + (k>>4))*512 + ((n&31)+32*((k>>3)&1))*8
// + (k&7), bf16.
// ---------------------------------------------------------------------------

// ---------------------------------------------------------------------------
// Stage 1: input LIF encoder -> spike i8 bytes. C=128. XLA-exact LIF.
// ---------------------------------------------------------------------------
__global__ void spike_encode_i8(const float* __restrict__ x,
                                uint4* __restrict__ s1)
{
    const int C = 128;
    int tid = blockIdx.x * blockDim.x + threadIdx.x;  // 65536 = 256*8*32
    int row = tid & 31;
    int kb  = (tid >> 5) & 7;
    int m_blk = tid >> 8;
    int m = m_blk * 32 + row;
    const float* px = x + (size_t)m * C + kb * 16;
    float xv[16];
#pragma unroll
    for (int j = 0; j < 16; j += 4) {
        float4 t4 = *(const float4*)(px + j);
        xv[j] = t4.x; xv[j+1] = t4.y; xv[j+2] = t4.z; xv[j+3] = t4.w;
    }
    float v[16];
#pragma unroll
    for (int j = 0; j < 16; ++j) v[j] = 0.0f;
#pragma unroll
    for (int t = 0; t < TSTEPS; ++t) {
        uint32_t dw[4] = {0u, 0u, 0u, 0u};
#pragma unroll
        for (int j = 0; j < 16; ++j) {
            float vv = __fadd_rn(v[j], __fmul_rn(__fsub_rn(xv[j], v[j]), 0.5f));
            bool sp = (vv >= 1.0f);
            dw[j >> 2] |= sp ? (1u << ((j & 3) * 8)) : 0u;
            v[j] = sp ? 0.0f : vv;
        }
        uint4 o; o.x = dw[0]; o.y = dw[1]; o.z = dw[2]; o.w = dw[3];
        s1[((size_t)(m_blk * 8 + kb) * 4 + t) * 32 + row] = o;
    }
}

// ---------------------------------------------------------------------------
// Weight prep: W [K][N] fp32 -> hi/lo bf16 split in B-frag layout.
// R16: coalesced 16B packet writes. Thread tid: nn=tid&31, oc=tid>>5;
// o2=oc&3 is the k-octet (8 consecutive k), oc>>2 selects hi|lo. Each wave
// writes one contiguous 1KB packet (64 lanes x 16B). Values and placement
// bitwise-identical to the R15 scalar version (k>>4 = k0>>4 + (o2>>1),
// (k>>3)&1 = o2&1, k&7 = j).
// ---------------------------------------------------------------------------
__global__ void split_transpose_all(const float* __restrict__ enc_W,
                                    const float* __restrict__ W_cells,
                                    bf16_t* __restrict__ W1h, bf16_t* __restrict__ W1l,
                                    bf16_t* __restrict__ W2h, bf16_t* __restrict__ W2l,
                                    bf16_t* __restrict__ W3h, bf16_t* __restrict__ W3l)
{
    const int N = 1024;
    const float* W;
    bf16_t *hi, *lo;
    int K;
    if (blockIdx.z == 0) {
        if (blockIdx.x >= 4) return;
        W = enc_W; hi = W1h; lo = W1l; K = 128;
    } else if (blockIdx.z == 1) {
        W = W_cells; hi = W2h; lo = W2l; K = 1024;
    } else {
        W = W_cells + (size_t)1024 * 1024; hi = W3h; lo = W3l; K = 1024;
    }
    const int NKB = K >> 4;
    __shared__ float tile[32][33];
    int k0 = blockIdx.x * 32, n0 = blockIdx.y * 32;
    int tx = threadIdx.x & 31, ty = threadIdx.x >> 5;
    for (int kk = ty; kk < 32; kk += 8)
        tile[kk][tx] = W[(size_t)(k0 + kk) * N + n0 + tx];
    __syncthreads();

    const int nn = tx;
    const int oc = ty;            // 0..7
    const int o2 = oc & 3;        // k-octet
    const bool isLo = (oc >> 2) != 0;
    const int kblk = (k0 >> 4) + (o2 >> 1);
    const int lane_in_packet = nn + 32 * (o2 & 1);

    frag_u f;
#pragma unroll
    for (int j = 0; j < 8; ++j) {
        float wv = tile[o2 * 8 + j][nn];
        bf16_t h = (bf16_t)wv;
        f.v[j] = isLo ? (bf16_t)(wv - (float)h) : h;
    }
    bf16_t* dst = (isLo ? lo : hi)
        + ((size_t)((n0 + nn) >> 5) * NKB + kblk) * 512 + lane_in_packet * 8;
    *(bf16x8*)dst = f.v;
}

// ---------------------------------------------------------------------------
// Fused MFMA GEMM + multistep LIF (identical to R15 -- the 41% plateau
// kernel; counters indicate compiler-codegen bound, not structural).
// ---------------------------------------------------------------------------
template <int K, bool LAST>
__global__ __launch_bounds__(256, 3)
void gemm_lif_mfma(const uint8_t* __restrict__ Abytes,
                   const bf16_t* __restrict__ Bh,
                   const bf16_t* __restrict__ Bl,
                   const float* __restrict__ bias,
                   uint8_t* __restrict__ Sbytes,
                   float* __restrict__ Out,
                   int M, int N)
{
    constexpr int NKB = K >> 4;                 // 8 or 64 (even)
    __shared__ __align__(8) unsigned short sh[4][256];   // [wave][row][kb][t]

    const int tid = threadIdx.x;
    const int lane = tid & 63;
    const int wid = tid >> 6;
    const int l31 = lane & 31;
    const int half = lane >> 5;

    int bid = blockIdx.x;
    const int n_t = bid & 15;                   // 16 n-tiles of 64 (2 per XCD)
    const int m_t = bid >> 4;                   // 128 m-tiles of 64
    const int m0 = m_t * 64, n0 = n_t * 64;
    const int wave_m = (wid & 1) * 32;
    const int wave_n = (wid >> 1) * 32;
    const int m_blk = (m0 + wave_m) >> 5;
    const int n_blk = (n0 + wave_n) >> 5;

    const uint8_t* pA = Abytes + (size_t)m_blk * NKB * 4 * 512 + l31 * 16 + half * 8;
    const bf16_t* pH = Bh + (size_t)n_blk * NKB * 512 + lane * 8;
    const bf16_t* pL = Bl + (size_t)n_blk * NKB * 512 + lane * 8;

    f32x16 acc[TSTEPS];
#pragma unroll
    for (int t = 0; t < TSTEPS; ++t)
        for (int rr = 0; rr < 16; ++rr) acc[t][rr] = 0.0f;

    uint2 fm[2][4];
    bf16x8 fh[2], fl[2];

#define LOADB(kb_, s_) {                                                     \
        fm[s_][0] = *(const uint2*)(pA + ((size_t)(kb_) * 4 + 0) * 512);     \
        fm[s_][1] = *(const uint2*)(pA + ((size_t)(kb_) * 4 + 1) * 512);     \
        fm[s_][2] = *(const uint2*)(pA + ((size_t)(kb_) * 4 + 2) * 512);     \
        fm[s_][3] = *(const uint2*)(pA + ((size_t)(kb_) * 4 + 3) * 512);     \
        fh[s_] = *(const bf16x8*)(pH + (kb_) * 512);                         \
        fl[s_] = *(const bf16x8*)(pL + (kb_) * 512);                         \
    }

#define EXPANDF(a_, f_) {                                                    \
        (f_).d[0] = __builtin_amdgcn_perm((a_).x, 0u, 0x00050004u) * 0x3F80u; \
        (f_).d[1] = __builtin_amdgcn_perm((a_).x, 0u, 0x00070006u) * 0x3F80u; \
        (f_).d[2] = __builtin_amdgcn_perm((a_).y, 0u, 0x00050004u) * 0x3F80u; \
        (f_).d[3] = __builtin_amdgcn_perm((a_).y, 0u, 0x00070006u) * 0x3F80u; \
    }

#define MFMASTEP(s_) {                                                       \
        frag_u af0, af1, af2, af3;                                           \
        EXPANDF(fm[s_][0], af0);                                             \
        EXPANDF(fm[s_][1], af1);                                             \
        EXPANDF(fm[s_][2], af2);                                             \
        EXPANDF(fm[s_][3], af3);                                             \
        acc[0] = __builtin_amdgcn_mfma_f32_32x32x16_bf16(af0.v, fh[s_], acc[0], 0, 0, 0); \
        acc[1] = __builtin_amdgcn_mfma_f32_32x32x16_bf16(af1.v, fh[s_], acc[1], 0, 0, 0); \
        acc[2] = __builtin_amdgcn_mfma_f32_32x32x16_bf16(af2.v, fh[s_], acc[2], 0, 0, 0); \
        acc[3] = __builtin_amdgcn_mfma_f32_32x32x16_bf16(af3.v, fh[s_], acc[3], 0, 0, 0); \
        acc[0] = __builtin_amdgcn_mfma_f32_32x32x16_bf16(af0.v, fl[s_], acc[0], 0, 0, 0); \
        acc[1] = __builtin_amdgcn_mfma_f32_32x32x16_bf16(af1.v, fl[s_], acc[1], 0, 0, 0); \
        acc[2] = __builtin_amdgcn_mfma_f32_32x32x16_bf16(af2.v, fl[s_], acc[2], 0, 0, 0); \
        acc[3] = __builtin_amdgcn_mfma_f32_32x32x16_bf16(af3.v, fl[s_], acc[3], 0, 0, 0); \
    }

#define STEP(kb_, s_) {                                                      \
        if ((kb_) + 1 < NKB) {                                               \
            LOADB((kb_) + 1, (s_) ^ 1);                                      \
            __builtin_amdgcn_s_waitcnt(VMCNT6);                              \
        } else {                                                             \
            __builtin_amdgcn_s_waitcnt(VMCNT0);                              \
        }                                                                    \
        asm volatile("" ::: "memory");                                       \
        MFMASTEP(s_);                                                        \
    }

    LOADB(0, 0);
#pragma unroll 2
    for (int kb = 0; kb < NKB; kb += 2) {
        STEP(kb + 0, 0);
        STEP(kb + 1, 1);
    }

#undef STEP
#undef MFMASTEP
#undef EXPANDF
#undef LOADB

    // --- LIF epilogue: t-scan in registers (XLA-exact arithmetic) ---
    const float bv = bias[n0 + wave_n + l31];
    f32x16 vmem;
#pragma unroll
    for (int rr = 0; rr < 16; ++rr) vmem[rr] = 0.0f;
    uint64_t bits = 0ull;
    unsigned short* myt = &sh[wid][0];          // [row][kb][t] = [32][2][4]

    const int NKBo = N >> 4;
    const int kbase = (n0 + wave_n) >> 4;

    for (int t = 0; t < TSTEPS; ++t) {
#pragma unroll
        for (int rr = 0; rr < 16; ++rr) {
            float y = __fadd_rn(acc[t][rr], bv);
            float vv = vmem[rr];
            vv = __fadd_rn(vv, __fmul_rn(__fsub_rn(y, vv), 0.5f));
            bool sp = (vv >= 1.0f);
            vmem[rr] = sp ? 0.0f : vv;
            if (LAST) {
                bits |= sp ? (1ull << (rr * 4 + t)) : 0ull;
            } else {
                unsigned long long b = __ballot(sp);
                if (l31 == 0) {
                    uint32_t hb = (uint32_t)(b >> (half * 32));
                    int rowi = (rr & 3) + 8 * (rr >> 2) + 4 * half;
                    myt[(rowi * 2 + 0) * 4 + t] = (unsigned short)hb;
                    myt[(rowi * 2 + 1) * 4 + t] = (unsigned short)(hb >> 16);
                }
            }
        }
    }

    if (LAST) {
#pragma unroll
        for (int rr = 0; rr < 16; ++rr) {
            int m_r = (rr & 3) + 8 * (rr >> 2) + 4 * half;
            int m = m0 + wave_m + m_r;
            int n = n0 + wave_n + l31;
            int cnt = __popc((unsigned)((bits >> (rr * 4)) & 0xFull));
            Out[(size_t)m * N + n] = 0.25f * (float)cnt;
        }
    } else {
        const ushort4v pk = *(const ushort4v*)&myt[(l31 * 2 + half) * 4];
#pragma unroll
        for (int t = 0; t < TSTEPS; ++t) {
            uint32_t m16 = pk[t];
            uint4 o;
            o.x = ((m16      ) & 0xFu) * 0x00204081u & 0x01010101u;
            o.y = ((m16 >>  4) & 0xFu) * 0x00204081u & 0x01010101u;
            o.z = ((m16 >>  8) & 0xFu) * 0x00204081u & 0x01010101u;
            o.w = ((m16 >> 12) & 0xFu) * 0x00204081u & 0x01010101u;
            *(uint4*)(Sbytes + ((((size_t)m_blk * NKBo + kbase + half) * 4 + t)
                                * 32 + l31) * 16) = o;
        }
    }
}

// ---------------------------------------------------------------------------
// Zero out2 (graph-capture-safe replacement for hipMemsetAsync).
// ---------------------------------------------------------------------------
__global__ void zero_out2(float* __restrict__ out2, int n)
{
    int i = blockIdx.x * blockDim.x + threadIdx.x;
    if (i < n) out2[i] = 0.0f;
}

// ---------------------------------------------------------------------------
// out2[b][d] += partial sums over L (8 chunks of 64, atomic, EXACT: all
// values are multiples of 2^-11 with total <= 1 -> fp32 adds are exact and
// order-independent -> bitwise-equal to the reference mean).
// ---------------------------------------------------------------------------
__global__ void mean_over_L_atomic(const float* __restrict__ out,
                                   float* __restrict__ out2,
                                   int B, int L, int D)
{
    int id = blockIdx.x * blockDim.x + threadIdx.x;   // B*D*8
    int bd = id & (B * D - 1);
    int chunk = id >> 14;                             // B*D = 16384 = 2^14
    int b = bd >> 10, d = bd & (D - 1);               // D = 1024
    const float* p = out + (size_t)b * L * D + (size_t)chunk * 64 * D + d;
    float s = 0.0f;
#pragma unroll 8
    for (int l = 0; l < 64; ++l) s += p[(size_t)l * D];
    atomicAdd(out2 + bd, s * (1.0f / 512.0f));
}

// ---------------------------------------------------------------------------
extern "C" void kernel_launch(void* const* d_in, const int* in_sizes, int n_in,
                              void* d_out, int out_size, void* d_ws, size_t ws_size,
                              hipStream_t stream)
{
    const float* inputs  = (const float*)d_in[0];  // [16,512,128]
    const float* enc_W   = (const float*)d_in[1];  // [128,1024]
    const float* enc_b   = (const float*)d_in[2];  // [1024]
    const float* W_cells = (const float*)d_in[3];  // [2,1024,1024]
    const float* b_cells = (const float*)d_in[4];  // [2,1024]

    const int B = 16, L = 512, C = 128, D = 1024;
    const int M = B * L;  // 8192

    // ws: s1 i8 4MB | W1h/l 0.5MB | W2h/l 4MB | W3h/l 4MB | h0 32MB | h1 32MB
    char* ws = (char*)d_ws;
    size_t off = 0;
    uint8_t* s1 = (uint8_t*)(ws + off);
    off += (size_t)(M / 32) * (C / 16) * 4 * 32 * 16;
    bf16_t* W1h = (bf16_t*)(ws + off); off += (size_t)C * D * 2;
    bf16_t* W1l = (bf16_t*)(ws + off); off += (size_t)C * D * 2;
    bf16_t* W2h = (bf16_t*)(ws + off); off += (size_t)D * D * 2;
    bf16_t* W2l = (bf16_t*)(ws + off); off += (size_t)D * D * 2;
    bf16_t* W3h = (bf16_t*)(ws + off); off += (size_t)D * D * 2;
    bf16_t* W3l = (bf16_t*)(ws + off); off += (size_t)D * D * 2;
    uint8_t* h0 = (uint8_t*)(ws + off);
    off += (size_t)(M / 32) * (D / 16) * 4 * 32 * 16;
    uint8_t* h1 = (uint8_t*)(ws + off);

    float* out  = (float*)d_out;          // [M, D]
    float* out2 = out + (size_t)M * D;    // [B, D]

    split_transpose_all<<<dim3(32, 32, 3), 256, 0, stream>>>(
        enc_W, W_cells, W1h, W1l, W2h, W2l, W3h, W3l);

    spike_encode_i8<<<256, 256, 0, stream>>>(inputs, (uint4*)s1);

    zero_out2<<<(B * D + 255) / 256, 256, 0, stream>>>(out2, B * D);

    const int nblocks = (M / 64) * (D / 64);   // 2048
    gemm_lif_mfma<128, false><<<nblocks, 256, 0, stream>>>(
        s1, W1h, W1l, enc_b, h0, nullptr, M, D);
    gemm_lif_mfma<1024, false><<<nblocks, 256, 0, stream>>>(
        h0, W2h, W2l, b_cells, h1, nullptr, M, D);
    gemm_lif_mfma<1024, true><<<nblocks, 256, 0, stream>>>(
        h1, W3h, W3l, b_cells + D, nullptr, out, M, D);

    mean_over_L_atomic<<<(B * D * 8) / 256, 256, 0, stream>>>(
        out, out2, B, L, D);
}